// Round 10
// baseline (90.875 us; speedup 1.0000x reference)
//
#include <hip/hip_runtime.h>
#include <hip/hip_bf16.h>
#include <stdint.h>

// NMS (YOLO-style) x=(16, 25200, 85) f32 -> out=(16, 300, 6) f32.
// R10: TWO graph nodes. K1 score (unchanged). K2 fuses select+sort+mask+
// jacobi+output per batch. Suppression is exactly class-local (offset boxes
// of different classes are >=7678 apart -> IoU exactly 0), so per-class
// bitmask iteration gives bit-identical supby rows at ~1us on-CU cost.

#define NB 16
#define NA 25200
#define NK 1024
#define ND 300
#define CAP 2048
#define NBIN 4096
#define NCLS 80

// monotone transform: larger float <=> larger uint32
__device__ __forceinline__ uint32_t fkey(float f) {
    uint32_t b = __float_as_uint(f);
    return (b & 0x80000000u) ? ~b : (b | 0x80000000u);
}

// linear bin over (0.25, 1); applied to the stored score float.
__device__ __forceinline__ int score_bin(float s) {
    float f = (s - 0.25f) * (4096.0f / 0.75f);
    int b = (int)f;
    return b > (NBIN - 1) ? (NBIN - 1) : (b < 0 ? 0 : b);
}

// ---------------- K1: per-anchor score / class / xyxy box ----------------
__global__ void score_kernel(const float* __restrict__ x,
                             float* __restrict__ scores,
                             int* __restrict__ clsid,
                             float4* __restrict__ boxes) {
    int b = blockIdx.y;
    int a = blockIdx.x * 16 + (threadIdx.x >> 4);
    int lane = threadIdx.x & 15;
    const float* p = x + (size_t)(b * NA + a) * 85;
    float obj = p[4];
    float best = -1e30f;
    int bi = 0;
#pragma unroll
    for (int r = 0; r < 5; ++r) {
        int j = lane + 16 * r;
        float v = obj * p[5 + j];
        if (v > best) { best = v; bi = j; }  // strict > : first max in-lane
    }
    for (int off = 8; off >= 1; off >>= 1) {
        float ov = __shfl_xor(best, off, 16);
        int   oi = __shfl_xor(bi,   off, 16);
        if (ov > best || (ov == best && oi < bi)) { best = ov; bi = oi; }
    }
    if (lane == 0) {
        bool q = best > 0.25f;
        scores[b * NA + a] = q ? best : -1.0f;
        clsid[b * NA + a] = bi;
        float cx = p[0], cy = p[1], w = p[2], h = p[3];
        boxes[b * NA + a] = make_float4(cx - w * 0.5f, cy - h * 0.5f,
                                        cx + w * 0.5f, cy + h * 0.5f);
    }
}

// ---- K2: select + sort + class-bucketed mask + Jacobi NMS + output ----
// One block per batch, 1024 threads.
__global__ void __launch_bounds__(1024)
fused_nms_kernel(const float* __restrict__ scores,
                 const float4* __restrict__ boxes,
                 const int* __restrict__ clsid,
                 float* __restrict__ out) {
    int b = blockIdx.x;
    int t = threadIdx.x;  // 1024
    int wid = t >> 6, lane = t & 63;

    // LDS overlays: smemA = sk (sort keys) then oboxS (offset boxes);
    //               smemB = lhist then dboxS (plain boxes).
    __shared__ __align__(16) char smemA[CAP * 8];   // 16 KiB
    __shared__ __align__(16) char smemB[NBIN * 4];  // 16 KiB
    __shared__ float2 dscl[NK];                     // 8 KiB (score, cls)
    __shared__ unsigned long long cmaskS[NCLS * 16];  // 10 KiB
    __shared__ unsigned long long aliveS[16];
    __shared__ unsigned int wsum[16];
    __shared__ int list[ND];
    __shared__ int sB;
    __shared__ unsigned int scnt;
    __shared__ int changedS;
    __shared__ int totalS;
    unsigned long long* sk = (unsigned long long*)smemA;
    float4* oboxS = (float4*)smemA;
    unsigned int* lhist = (unsigned int*)smemB;
    float4* dboxS = (float4*)smemB;

    // --- phase A0: zero + build LDS histogram (float4 stream) ---
    ((uint4*)lhist)[t] = make_uint4(0u, 0u, 0u, 0u);
    sk[t] = 0ULL; sk[t + 1024] = 0ULL;
    cmaskS[t] = 0ULL;
    if (t < NCLS * 16 - 1024) cmaskS[1024 + t] = 0ULL;
    if (t == 0) { sB = -1; scnt = 0u; }
    __syncthreads();
    const float* sc = scores + b * NA;
    const float4* sc4 = (const float4*)sc;  // NA % 4 == 0, 16B-aligned
    for (int i = t; i < NA / 4; i += 1024) {
        float4 s4 = sc4[i];
        if (s4.x > 0.25f) atomicAdd(&lhist[score_bin(s4.x)], 1u);
        if (s4.y > 0.25f) atomicAdd(&lhist[score_bin(s4.y)], 1u);
        if (s4.z > 0.25f) atomicAdd(&lhist[score_bin(s4.z)], 1u);
        if (s4.w > 0.25f) atomicAdd(&lhist[score_bin(s4.w)], 1u);
    }
    __syncthreads();

    // --- phase A: suffix scan via wave shfl ---
    uint4 hv = ((const uint4*)lhist)[t];  // bins t*4 .. t*4+3
    unsigned int mysum = hv.x + hv.y + hv.z + hv.w;
    unsigned int ssfx = mysum;
#pragma unroll
    for (int off = 1; off < 64; off <<= 1) {
        unsigned int v = __shfl_down(ssfx, off);
        if (lane + off < 64) ssfx += v;
    }
    if (lane == 0) wsum[wid] = ssfx;
    __syncthreads();
    unsigned int tail = 0;
    for (int w2 = wid + 1; w2 < 16; ++w2) tail += wsum[w2];
    unsigned int S_t = ssfx + tail;
    unsigned int Snext = S_t - mysum;
    unsigned int s3 = hv.w + Snext;
    unsigned int s2 = hv.z + s3;
    unsigned int s1 = hv.y + s2;
    unsigned int s0 = hv.x + s1;
    int loc = -1;
    if (s3 >= NK) loc = t * 4 + 3;
    else if (s2 >= NK) loc = t * 4 + 2;
    else if (s1 >= NK) loc = t * 4 + 1;
    else if (s0 >= NK) loc = t * 4 + 0;
#pragma unroll
    for (int off = 32; off >= 1; off >>= 1) {
        int o = __shfl_xor(loc, off);
        loc = o > loc ? o : loc;
    }
    if ((t & 63) == 0) atomicMax(&sB, loc);
    __syncthreads();
    int B = sB < 0 ? 0 : sB;

    // --- phase B: compact candidates into LDS (float4 stream) ---
    for (int i = t; i < NA / 4; i += 1024) {
        float4 s4 = sc4[i];
        float se[4] = {s4.x, s4.y, s4.z, s4.w};
#pragma unroll
        for (int e = 0; e < 4; ++e) {
            float s = se[e];
            int a = i * 4 + e;
            bool q = (s > 0.25f) && (score_bin(s) >= B);
            unsigned long long m = __ballot(q);
            if (q) {
                int nbelow = __popcll(m & ((1ULL << lane) - 1));
                int leader = __ffsll((long long)m) - 1;
                unsigned int base = 0;
                if (lane == leader)
                    base = atomicAdd(&scnt, (unsigned int)__popcll(m));
                base = __shfl(base, leader);
                unsigned int pos = base + nbelow;
                if (pos < CAP)
                    sk[pos] =
                        ((unsigned long long)fkey(s) << 32) | (uint32_t)(~a);
            }
        }
    }
    __syncthreads();

    // --- phase C: register bitonic sort (descending) ---
    const int e1 = t, e2 = t + 1024;
    unsigned long long v1 = sk[e1];
    unsigned long long v2 = sk[e2];
    __syncthreads();
    for (int k = 2; k <= CAP; k <<= 1) {
        for (int j = k >> 1; j > 0; j >>= 1) {
            if (j >= 1024) {
                unsigned long long lo = v1 < v2 ? v1 : v2;
                unsigned long long hi = v1 < v2 ? v2 : v1;
                v1 = hi; v2 = lo;
            } else if (j >= 64) {
                sk[e1] = v1; sk[e2] = v2;
                __syncthreads();
                unsigned long long p1 = sk[e1 ^ j], p2 = sk[e2 ^ j];
                __syncthreads();
                {
                    bool takeMax = (((e1 & j) == 0) == ((e1 & k) == 0));
                    bool g = p1 > v1;
                    v1 = (takeMax == g) ? p1 : v1;
                }
                {
                    bool takeMax = (((e2 & j) == 0) == ((e2 & k) == 0));
                    bool g = p2 > v2;
                    v2 = (takeMax == g) ? p2 : v2;
                }
            } else {
                {
                    unsigned long long p1 =
                        (unsigned long long)__shfl_xor((long long)v1, j);
                    bool takeMax = (((e1 & j) == 0) == ((e1 & k) == 0));
                    bool g = p1 > v1;
                    v1 = (takeMax == g) ? p1 : v1;
                }
                {
                    unsigned long long p2 =
                        (unsigned long long)__shfl_xor((long long)v2, j);
                    bool takeMax = (((e2 & j) == 0) == ((e2 & k) == 0));
                    bool g = p2 > v2;
                    v2 = (takeMax == g) ? p2 : v2;
                }
            }
        }
    }

    // --- phase D: decode rank-t winner, stage into LDS, class buckets ---
    unsigned long long key = v1;
    uint32_t u = (uint32_t)(key >> 32);
    int a = (u == 0) ? 0 : (int)(~(uint32_t)key);  // pad-safe index
    uint32_t fb = (u & 0x80000000u) ? (u ^ 0x80000000u) : ~u;
    float s = __uint_as_float(fb);  // masked score (NaN for pad)
    float4 bx = boxes[b * NA + a];
    int ci = clsid[b * NA + a];
    float c = (float)ci;
    float off = c * 7680.0f;
    float4 ob = make_float4(bx.x + off, bx.y + off, bx.z + off, bx.w + off);
    bool keep0 = s > 0.25f;  // false for pad (NaN)
    unsigned long long bal = __ballot(keep0);
    if (lane == 0) aliveS[wid] = bal;
    __syncthreads();  // sk reads done (phase C barriers) -> safe to overlay
    oboxS[t] = ob;
    dboxS[t] = bx;
    dscl[t] = make_float2(s, c);
    atomicOr(&cmaskS[ci * 16 + wid], 1ULL << lane);
    __syncthreads();

    // --- phase E: supby row via class bucket (bit-identical to full mask:
    // cross-class IoU is exactly 0 since offset gap >= 7678 > box span) ---
    unsigned long long row[16];
#pragma unroll
    for (int w = 0; w < 16; ++w) row[w] = 0ULL;
    float4 r4 = ob;
    float ra = (r4.z - r4.x) * (r4.w - r4.y);
    for (int w = 0; w <= wid; ++w) {
        unsigned long long bits = cmaskS[ci * 16 + w];
        if (w == wid)
            bits &= (lane == 0) ? 0ULL : ((1ULL << lane) - 1ULL);  // j < t
        unsigned long long rbits = 0ULL;
        while (bits) {
            int bit = __ffsll((long long)bits) - 1;
            bits &= bits - 1;
            float4 o = oboxS[w * 64 + bit];
            float carea = (o.z - o.x) * (o.w - o.y);
            float ix1 = fmaxf(r4.x, o.x), iy1 = fmaxf(r4.y, o.y);
            float ix2 = fminf(r4.z, o.z), iy2 = fminf(r4.w, o.w);
            float iw = fmaxf(ix2 - ix1, 0.0f), ih = fmaxf(iy2 - iy1, 0.0f);
            float inter = iw * ih;
            float uni = ra + carea - inter;
            float iou = inter / (uni + 1e-9f);
            if (iou > 0.45f) rbits |= (1ULL << bit);
        }
        row[w] = rbits;
    }
    __syncthreads();

    // --- phase F: Jacobi fixed-point NMS ---
    for (int it = 0; it < NK; ++it) {
        if (t == 0) changedS = 0;
        unsigned long long aw[16];
#pragma unroll
        for (int w = 0; w < 16; ++w) aw[w] = aliveS[w];  // snapshot
        __syncthreads();
        unsigned long long sup = 0;
#pragma unroll
        for (int w = 0; w < 16; ++w) sup |= aw[w] & row[w];
        bool newalive = keep0 && (sup == 0);
        unsigned long long nb = __ballot(newalive);
        if (lane == 0) {
            if (nb != aw[wid]) { atomicOr(&changedS, 1); aliveS[wid] = nb; }
        }
        __syncthreads();
        if (!changedS) break;
    }

    // --- phase G: ordered kept list + output ---
    if (t < 64) {
        unsigned long long av = (lane < 16) ? aliveS[lane] : 0ULL;
        int cnt = (lane < 16) ? __popcll(av) : 0;
        int pre = cnt;
        for (int off2 = 1; off2 < 64; off2 <<= 1) {
            int v = __shfl_up(pre, off2);
            if (lane >= off2) pre += v;
        }
        int total = __shfl(pre, 63);
        int base = pre - cnt;
        if (lane == 0) totalS = total;
        if (lane < 16) {
            unsigned long long m = av;
            int pos = base;
            while (m && pos < ND) {
                int bit = __ffsll((long long)m) - 1;
                list[pos++] = lane * 64 + bit;
                m &= m - 1;
            }
        }
    }
    __syncthreads();
    if (t < ND) {
        float vals[6] = {0, 0, 0, 0, 0, 0};
        if (t < totalS) {
            int i = list[t];
            float4 db = dboxS[i];
            float2 sl = dscl[i];
            vals[0] = db.x; vals[1] = db.y; vals[2] = db.z; vals[3] = db.w;
            vals[4] = sl.x; vals[5] = sl.y;
        }
        float* o = out + (size_t)(b * ND + t) * 6;
#pragma unroll
        for (int c2 = 0; c2 < 6; ++c2) o[c2] = vals[c2];
    }
}

extern "C" void kernel_launch(void* const* d_in, const int* in_sizes, int n_in,
                              void* d_out, int out_size, void* d_ws, size_t ws_size,
                              hipStream_t stream) {
    const float* x = (const float*)d_in[0];
    float* out = (float*)d_out;

    char* ws = (char*)d_ws;
    size_t off = 0;
    auto alloc = [&](size_t bytes) {
        void* p = ws + off;
        off += (bytes + 255) & ~(size_t)255;
        return p;
    };
    float* scores = (float*)alloc((size_t)NB * NA * sizeof(float));
    int* clsid = (int*)alloc((size_t)NB * NA * sizeof(int));
    float4* boxes = (float4*)alloc((size_t)NB * NA * sizeof(float4));
    (void)ws_size;

    score_kernel<<<dim3(NA / 16, NB), 256, 0, stream>>>(x, scores, clsid,
                                                        boxes);
    fused_nms_kernel<<<NB, 1024, 0, stream>>>(scores, boxes, clsid, out);
}